// Round 8
// baseline (141.549 us; speedup 1.0000x reference)
//
#include <hip/hip_runtime.h>
#include <math.h>

// Renderer: occupancy-field ray marching + secant + shading.
// R8: R6 math, but the per-ray reparam weight table (4 KB/block, float4
//     pair-major) lives in GLOBAL d_ws instead of LDS: broadcast
//     global_load_dwordx4 reads ride the vector-mem pipe (L1-resident),
//     unloading the per-CU LDS pipe which R5-R7 counters indicate is the
//     shared bottleneck (occupancy-invariant runtime). Shuffles + sval stay
//     on LDS (small). Template fallback to LDS tables if ws_size too small.

namespace {

constexpr int H_    = 128;
constexpr int RS    = 128;   // RAY_STEPS
constexpr int NSEC  = 8;
constexpr int SOUT_ = 32;    // STEPS_OUT
constexpr int SIN_  = 64;    // STEPS_IN
constexpr int FULL_ = 96;
constexpr float EPSA   = 1e-6f;
constexpr float DELTA_ = 0.44626032029685964f; // max(2*exp(-1.5), 0.1)
constexpr float L2E    = 1.4426950408889634f;  // log2(e)
constexpr float LN2    = 0.6931471805599453f;

typedef __attribute__((ext_vector_type(2))) float f2;

__device__ __forceinline__ f2 s2(float v) { return f2{v, v}; }

// deg-6 poly for log2(1+e), e in [0,1], via t = 2e-1; max err ~1e-4.
constexpr float PC0 =  0.5849625007211562f;
constexpr float PC1 =  0.4808983469629878f;
constexpr float PC2 = -0.0801497244938313f;
constexpr float PC3 =  0.0178110498875181f;
constexpr float PC4 = -0.0044527624718795f;
constexpr float PC5 =  0.0011873633258345f;
constexpr float PC6 = -0.0003298231460651f;

// packed log2-domain softplus: sp2(u) = max(u,0) + log2(1 + 2^-|u|)
__device__ __forceinline__ f2 sp2p(f2 u) {
    f2 e;
    e.x = __builtin_amdgcn_exp2f(-fabsf(u.x));
    e.y = __builtin_amdgcn_exp2f(-fabsf(u.y));
    f2 t = e + e - 1.0f;
    f2 p = s2(PC6);
    p = __builtin_elementwise_fma(p, t, s2(PC5));
    p = __builtin_elementwise_fma(p, t, s2(PC4));
    p = __builtin_elementwise_fma(p, t, s2(PC3));
    p = __builtin_elementwise_fma(p, t, s2(PC2));
    p = __builtin_elementwise_fma(p, t, s2(PC1));
    p = __builtin_elementwise_fma(p, t, s2(PC0));
    return __builtin_elementwise_max(u, s2(0.0f)) + p;
}

__device__ __forceinline__ float sigmoid_fast(float x) {
    return __builtin_amdgcn_rcpf(1.0f + __expf(-x));
}
__device__ __forceinline__ float sgnf(float p) {
    return (p > 0.0f) ? 1.0f : ((p < 0.0f) ? -1.0f : 0.0f);
}
__device__ __forceinline__ float secant_step(float f_l, float f_h, float d_l, float d_h) {
    float den = f_h - f_l;
    if (fabsf(den) > 1e-12f) return -f_l * (d_h - d_l) / den + d_l;
    return 0.5f * (d_l + d_h);
}

__device__ void inv4(const float* m, float* o) {
    float inv[16];
    inv[0]  =  m[5]*m[10]*m[15] - m[5]*m[11]*m[14] - m[9]*m[6]*m[15] + m[9]*m[7]*m[14] + m[13]*m[6]*m[11] - m[13]*m[7]*m[10];
    inv[4]  = -m[4]*m[10]*m[15] + m[4]*m[11]*m[14] + m[8]*m[6]*m[15] - m[8]*m[7]*m[14] - m[12]*m[6]*m[11] + m[12]*m[7]*m[10];
    inv[8]  =  m[4]*m[9]*m[15]  - m[4]*m[11]*m[13] - m[8]*m[5]*m[15] + m[8]*m[7]*m[13] + m[12]*m[5]*m[11] - m[12]*m[7]*m[9];
    inv[12] = -m[4]*m[9]*m[14]  + m[4]*m[10]*m[13] + m[8]*m[5]*m[14] - m[8]*m[6]*m[13] - m[12]*m[5]*m[10] + m[12]*m[6]*m[9];
    inv[1]  = -m[1]*m[10]*m[15] + m[1]*m[11]*m[14] + m[9]*m[2]*m[15] - m[9]*m[3]*m[14] - m[13]*m[2]*m[11] + m[13]*m[3]*m[10];
    inv[5]  =  m[0]*m[10]*m[15] - m[0]*m[11]*m[14] - m[8]*m[2]*m[15] + m[8]*m[3]*m[14] + m[12]*m[2]*m[11] - m[12]*m[3]*m[10];
    inv[9]  = -m[0]*m[9]*m[15]  + m[0]*m[11]*m[13] + m[8]*m[1]*m[15] - m[8]*m[3]*m[13] - m[12]*m[1]*m[11] + m[12]*m[3]*m[9];
    inv[13] =  m[0]*m[9]*m[14]  - m[0]*m[10]*m[13] - m[8]*m[1]*m[14] + m[8]*m[2]*m[13] + m[12]*m[1]*m[10] - m[12]*m[2]*m[9];
    inv[2]  =  m[1]*m[6]*m[15]  - m[1]*m[7]*m[14]  - m[5]*m[2]*m[15] + m[5]*m[3]*m[14] + m[13]*m[2]*m[7]  - m[13]*m[3]*m[6];
    inv[6]  = -m[0]*m[6]*m[15]  + m[0]*m[7]*m[14]  + m[4]*m[2]*m[15] - m[4]*m[3]*m[14] - m[12]*m[2]*m[7]  + m[12]*m[3]*m[6];
    inv[10] =  m[0]*m[5]*m[15]  - m[0]*m[7]*m[13]  - m[4]*m[1]*m[15] + m[4]*m[3]*m[13] + m[12]*m[1]*m[7]  - m[12]*m[3]*m[5];
    inv[14] = -m[0]*m[5]*m[14]  + m[0]*m[6]*m[13]  + m[4]*m[1]*m[14] - m[4]*m[2]*m[13] - m[12]*m[1]*m[6]  + m[12]*m[2]*m[5];
    inv[3]  = -m[1]*m[6]*m[11]  + m[1]*m[7]*m[10]  + m[5]*m[2]*m[11] - m[5]*m[3]*m[10] - m[9]*m[2]*m[7]   + m[9]*m[3]*m[6];
    inv[7]  =  m[0]*m[6]*m[11]  - m[0]*m[7]*m[10]  - m[4]*m[2]*m[11] + m[4]*m[3]*m[10] + m[8]*m[2]*m[7]   - m[8]*m[3]*m[6];
    inv[11] = -m[0]*m[5]*m[11]  + m[0]*m[7]*m[9]   + m[4]*m[1]*m[11] - m[4]*m[3]*m[9]  - m[8]*m[1]*m[7]   + m[8]*m[3]*m[5];
    inv[15] =  m[0]*m[5]*m[10]  - m[0]*m[6]*m[9]   - m[4]*m[1]*m[10] + m[4]*m[2]*m[9]  + m[8]*m[1]*m[6]   - m[8]*m[2]*m[5];
    float det = m[0]*inv[0] + m[1]*inv[4] + m[2]*inv[8] + m[3]*inv[12];
    float idet = 1.0f / det;
    for (int i = 0; i < 16; i++) o[i] = inv[i] * idet;
}

template <bool GT>
__global__ __launch_bounds__(64) void render_k(
    const float* __restrict__ pixels,
    const float* __restrict__ Cm, const float* __restrict__ Wm, const float* __restrict__ Sm,
    const float* __restrict__ W1, const float* __restrict__ b1,
    const float* __restrict__ W2, const float* __restrict__ b2,
    const float* __restrict__ Wc1, const float* __restrict__ bc1,
    const float* __restrict__ Wc2, const float* __restrict__ bc2,
    float4* ws4,                    // global table base (GT) or null
    float* __restrict__ out, int N)
{
    const int tid = threadIdx.x;      // 0..63, one wave
    const int r   = blockIdx.x;       // one ray per block

    // pair-major weight tables: slot j2 holds hidden units 2*j2, 2*j2+1
    __shared__ float4 sP0[GT ? 1 : H_/2];   // {a,a', c,c'}     (occ, log2 dom)
    __shared__ float4 sP1[GT ? 1 : H_/2];   // {w,w', aC,aC'}   (w = w2*ln2)
    __shared__ float4 sP2[GT ? 1 : H_/2];   // {cC,cC', w0,w0'}
    __shared__ float4 sP3[GT ? 1 : H_/2];   // {w1,w1', w2,w2'}
    __shared__ float  sval[RS];       // phase-1 logits
    __shared__ float  sInv[3][16];    // iC, iW, iS
    __shared__ float  sT[16], sM[16];

    float4* gT = GT ? (ws4 + (size_t)r * 256) : nullptr;  // 4 tables x 64

    // ---- geometry: one inv4 per matrix on lanes 0..2 ----
    {
        const float* mm = (tid == 0) ? Cm : ((tid == 1) ? Wm : Sm);
        float o[16];
        inv4(mm, o);
        if (tid < 3)
            for (int k = 0; k < 16; k++) sInv[tid][k] = o[k];
    }
    __syncthreads();
    if (tid < 16) {                   // T = iW @ iC
        int row = tid >> 2, col = tid & 3;
        float s = 0.0f;
        for (int k = 0; k < 4; k++) s += sInv[1][row*4 + k] * sInv[0][k*4 + col];
        sT[tid] = s;
    }
    __syncthreads();
    if (tid < 16) {                   // M = iS @ T
        int row = tid >> 2, col = tid & 3;
        float s = 0.0f;
        for (int k = 0; k < 4; k++) s += sInv[2][row*4 + k] * sT[k*4 + col];
        sM[tid] = s;
    }
    __syncthreads();

    float cx, cy, cz, rx, ry, rz, dfar;
    int mint;
    {
        const float px_ = pixels[2*r], py_ = pixels[2*r + 1];
        float cam[3], dir[3];
        for (int i = 0; i < 3; i++) {
            cam[i] = sM[4*i + 3];
            float pw = sM[4*i + 0]*px_ + sM[4*i + 1]*py_ + sM[4*i + 2] + sM[4*i + 3];
            dir[i] = pw - cam[i];
        }
        float nrm = sqrtf(dir[0]*dir[0] + dir[1]*dir[1] + dir[2]*dir[2]);
        rx = dir[0]/nrm; ry = dir[1]/nrm; rz = dir[2]/nrm;
        cx = cam[0]; cy = cam[1]; cz = cam[2];
        float rcd = rx*cx + ry*cy + rz*cz;
        float cc  = cx*cx + cy*cy + cz*cz;
        float under = rcd*rcd - (cc - 1.0f);      // RADIUS = 1
        mint = under > 0.0f;
        float s = sqrtf(mint ? under : 1.0f);
        dfar = mint ? fmaxf(s - rcd, 0.0f) : 0.0f;
    }

    // ---- staging + reparam: lane stages hidden units 2*tid, 2*tid+1 ----
    float a2k[2], c2k[2], w2k[2];               // occ (secant + fast path)
    float cCr[2], w0r[2], w1r[2], w2r[2];       // color (fast path)
    {
        float aCk[2];
#pragma unroll
        for (int k = 0; k < 2; k++) {
            const int u = 2*tid + k;
            float w1x = W1[u], w1y = W1[H_ + u], w1z = W1[2*H_ + u];
            float b1j = b1[u], w2j = W2[u];
            a2k[k] = (w1x*rx + w1y*ry + w1z*rz) * L2E;
            c2k[k] = (w1x*cx + w1y*cy + w1z*cz + b1j) * L2E;
            w2k[k] = w2j * LN2;
            float q0 = Wc1[u],        q1 = Wc1[H_ + u],  q2 = Wc1[2*H_ + u];
            float q3 = Wc1[3*H_ + u], q4 = Wc1[4*H_ + u], q5 = Wc1[5*H_ + u];
            aCk[k] = q0*rx + q1*ry + q2*rz;
            cCr[k] = q0*cx + q1*cy + q2*cz + bc1[u] - (q3*rx + q4*ry + q5*rz);
            w0r[k] = Wc2[3*u + 0]; w1r[k] = Wc2[3*u + 1]; w2r[k] = Wc2[3*u + 2];
        }
        float4 t0 = make_float4(a2k[0], a2k[1], c2k[0], c2k[1]);
        float4 t1 = make_float4(w2k[0], w2k[1], aCk[0], aCk[1]);
        float4 t2 = make_float4(cCr[0], cCr[1], w0r[0], w0r[1]);
        float4 t3 = make_float4(w1r[0], w1r[1], w2r[0], w2r[1]);
        if constexpr (GT) {
            gT[tid]       = t0;
            gT[64 + tid]  = t1;
            gT[128 + tid] = t2;
            gT[192 + tid] = t3;
        } else {
            sP0[tid] = t0; sP1[tid] = t1; sP2[tid] = t2; sP3[tid] = t3;
        }
    }
    const float b2v  = b2[0];
    const float bc20 = bc2[0], bc21 = bc2[1], bc22 = bc2[2];
    __syncthreads();

    // table accessors (by value)
    auto LD0 = [&](int j) -> float4 { if constexpr (GT) return gT[j];       else return sP0[j]; };
    auto LD1 = [&](int j) -> float4 { if constexpr (GT) return gT[64 + j];  else return sP1[j]; };
    auto LD2 = [&](int j) -> float4 { if constexpr (GT) return gT[128 + j]; else return sP2[j]; };
    auto LD3 = [&](int j) -> float4 { if constexpr (GT) return gT[192 + j]; else return sP3[j]; };

    float alpha0, r0c, g0c, b0c;      // sample tid
    float alpha1, r1c, g1c, b1c;      // sample 64 + (tid&31)

    if (dfar == 0.0f) {
        // ---- fast path: all 96 samples sit at the camera point ----
        f2 sp = sp2p(f2{c2k[0], c2k[1]});
        float part = sp.x*w2k[0] + sp.y*w2k[1];
        f2 ff = __builtin_elementwise_max(f2{cCr[0], cCr[1]}, s2(0.0f));
        float A0 = ff.x*w0r[0] + ff.y*w0r[1];
        float A1 = ff.x*w1r[0] + ff.y*w1r[1];
        float A2 = ff.x*w2r[0] + ff.y*w2r[1];
#pragma unroll
        for (int off = 32; off; off >>= 1) {
            part += __shfl_xor(part, off, 64);
            A0   += __shfl_xor(A0,   off, 64);
            A1   += __shfl_xor(A1,   off, 64);
            A2   += __shfl_xor(A2,   off, 64);
        }
        alpha0 = sigmoid_fast(part + b2v);
        r0c = sigmoid_fast(A0 + bc20);
        g0c = sigmoid_fast(A1 + bc21);
        b0c = sigmoid_fast(A2 + bc22);
        alpha1 = alpha0; r1c = r0c; g1c = g0c; b1c = b0c;
    } else {
        // ---- phase 1: steps tid and tid+64, packed over the step pair ----
        const float inv127 = 1.0f / (RS - 1);
        float l_a, l_b;
        {
            f2 d2 = f2{ dfar * ((float)tid * inv127),
                        dfar * ((float)(tid + 64) * inv127) };
            f2 acc = s2(0.0f);
#pragma unroll 4
            for (int j2 = 0; j2 < H_/2; j2++) {
                float4 q0 = LD0(j2);
                float4 q1 = LD1(j2);
                f2 uA = __builtin_elementwise_fma(s2(q0.x), d2, s2(q0.z));
                f2 uB = __builtin_elementwise_fma(s2(q0.y), d2, s2(q0.w));
                acc = __builtin_elementwise_fma(sp2p(uA), s2(q1.x), acc);
                acc = __builtin_elementwise_fma(sp2p(uB), s2(q1.y), acc);
            }
            l_a = acc.x + b2v;
            l_b = acc.y + b2v;
            sval[tid] = l_a; sval[tid + 64] = l_b;
        }
        __syncthreads();

        // ---- phase 2: crossing detection + secant (val = sigmoid-0.5) ----
        float dnp, dfp;
        int obj;
        {
            float va = sigmoid_fast(l_a) - 0.5f;
            float vb = sigmoid_fast(l_b) - 0.5f;
            float van = __shfl_down(va, 1, 64);
            float vb0 = __shfl(vb, 0, 64);
            if (tid == 63) van = vb0;
            float vbn = __shfl_down(vb, 1, 64);
            float ca = sgnf(va * van) * (float)(RS - tid);
            float cb = (tid < 63) ? sgnf(vb * vbn) * (float)(64 - tid) : 1.0f;
            float cmin = ca; int ind = tid;
            if (cb < cmin) { cmin = cb; ind = tid + 64; }
#pragma unroll
            for (int off = 32; off; off >>= 1) {
                float c2 = __shfl_xor(cmin, off, 64);
                int   i2 = __shfl_xor(ind,  off, 64);
                if (c2 < cmin || (c2 == cmin && i2 < ind)) { cmin = c2; ind = i2; }
            }
            const int mask_0_free = (__shfl(va, 0, 64) < 0.0f);
            const int mask_sc = cmin < 0.0f;
            const int ind_hi = min(ind + 1, RS - 1);
            const float f_low  = sigmoid_fast(sval[ind])    - 0.5f;
            const float f_high = sigmoid_fast(sval[ind_hi]) - 0.5f;
            const float d_low  = dfar * ((float)ind    * inv127);
            const float d_high = dfar * ((float)ind_hi * inv127);
            const int msk = mask_sc && (f_low < 0.0f) && mint && mask_0_free;

            float d_p = secant_step(f_low, f_high, d_low, d_high);
            if (msk) {   // wave-uniform
                float d_l = d_low, f_l = f_low, d_h = d_high, f_h = f_high;
                for (int it = 0; it < NSEC; it++) {
                    f2 u2 = __builtin_elementwise_fma(f2{a2k[0], a2k[1]}, s2(d_p),
                                                      f2{c2k[0], c2k[1]});
                    f2 sp = sp2p(u2);
                    float part = sp.x*w2k[0] + sp.y*w2k[1];
#pragma unroll
                    for (int off = 32; off; off >>= 1) part += __shfl_xor(part, off, 64);
                    float fm = sigmoid_fast(part + b2v) - 0.5f;
                    bool low = fm < 0.0f;
                    d_l = low ? d_p : d_l;  f_l = low ? fm : f_l;
                    d_h = low ? d_h : d_p;  f_h = low ? f_h : fm;
                    d_p = secant_step(f_l, f_h, d_l, d_h);
                }
            }
            float d_i;
            if (!mask_0_free)      d_i = 0.0f;
            else if (msk)          d_i = d_p;
            else                   d_i = INFINITY;
            int mask_zero = (d_i == 0.0f);
            int mask_pred = isfinite(d_i);
            float dists = mask_pred ? d_i : 1.0f;
            if (mask_zero) dists = 0.0f;
            obj = mask_pred && !mask_zero;
            dnp = fmaxf(dists - DELTA_, 0.0f);
            dfp = fminf(dists + DELTA_, dfar);
        }

        auto sample_d = [&](int s) -> float {
            if (obj) {
                if (s < SOUT_) return dnp * ((float)s * (1.0f / (SOUT_ - 1)));
                float u = (float)(s - SOUT_) * (1.0f / (SIN_ - 1));
                return dnp * (1.0f - u) + dfp * u;
            }
            return dfar * ((float)s * (1.0f / (FULL_ - 1)));
        };

        // ---- phase 3, pass 0: samples 0..63, hidden units paired ----
        {
            const f2 dd = s2(sample_d(tid));
            f2 SO = s2(0.0f), A0 = s2(0.0f), A1 = s2(0.0f), A2 = s2(0.0f);
#pragma unroll 4
            for (int j2 = 0; j2 < H_/2; j2++) {
                float4 q0 = LD0(j2);
                float4 q1 = LD1(j2);
                float4 q2 = LD2(j2);
                float4 q3 = LD3(j2);
                f2 u = __builtin_elementwise_fma(f2{q0.x, q0.y}, dd, f2{q0.z, q0.w});
                SO = __builtin_elementwise_fma(sp2p(u), f2{q1.x, q1.y}, SO);
                f2 f = __builtin_elementwise_max(
                           __builtin_elementwise_fma(f2{q1.z, q1.w}, dd, f2{q2.x, q2.y}),
                           s2(0.0f));
                A0 = __builtin_elementwise_fma(f, f2{q2.z, q2.w}, A0);
                A1 = __builtin_elementwise_fma(f, f2{q3.x, q3.y}, A1);
                A2 = __builtin_elementwise_fma(f, f2{q3.z, q3.w}, A2);
            }
            alpha0 = sigmoid_fast(SO.x + SO.y + b2v);
            r0c = sigmoid_fast(A0.x + A0.y + bc20);
            g0c = sigmoid_fast(A1.x + A1.y + bc21);
            b0c = sigmoid_fast(A2.x + A2.y + bc22);
        }

        // ---- phase 3, pass 1: samples 64..95; pair-range split by half-wave ----
        {
            const int s1 = 64 + (tid & 31);
            const int jb = (tid >> 5) * (H_/4);   // 0 or 32 pair-slots
            const f2 dd = s2(sample_d(s1));
            f2 SO = s2(0.0f), A0 = s2(0.0f), A1 = s2(0.0f), A2 = s2(0.0f);
#pragma unroll 4
            for (int j2 = jb; j2 < jb + H_/4; j2++) {
                float4 q0 = LD0(j2);
                float4 q1 = LD1(j2);
                float4 q2 = LD2(j2);
                float4 q3 = LD3(j2);
                f2 u = __builtin_elementwise_fma(f2{q0.x, q0.y}, dd, f2{q0.z, q0.w});
                SO = __builtin_elementwise_fma(sp2p(u), f2{q1.x, q1.y}, SO);
                f2 f = __builtin_elementwise_max(
                           __builtin_elementwise_fma(f2{q1.z, q1.w}, dd, f2{q2.x, q2.y}),
                           s2(0.0f));
                A0 = __builtin_elementwise_fma(f, f2{q2.z, q2.w}, A0);
                A1 = __builtin_elementwise_fma(f, f2{q3.x, q3.y}, A1);
                A2 = __builtin_elementwise_fma(f, f2{q3.z, q3.w}, A2);
            }
            float SOs = SO.x + SO.y, A0s = A0.x + A0.y;
            float A1s = A1.x + A1.y, A2s = A2.x + A2.y;
            SOs += __shfl_xor(SOs, 32, 64);
            A0s += __shfl_xor(A0s, 32, 64);
            A1s += __shfl_xor(A1s, 32, 64);
            A2s += __shfl_xor(A2s, 32, 64);
            alpha1 = sigmoid_fast(SOs + b2v);
            r1c = sigmoid_fast(A0s + bc20);
            g1c = sigmoid_fast(A1s + bc21);
            b1c = sigmoid_fast(A2s + bc22);
        }
    }

    // ---- compositing: in-register wave scan over 96 ordered samples ----
    {
        float mA = 1.0f - alpha0 + EPSA;
        float p = mA;
#pragma unroll
        for (int off = 1; off < 64; off <<= 1) {
            float v = __shfl_up(p, off, 64);
            if (tid >= off) p *= v;
        }
        float TexA = __shfl_up(p, 1, 64);
        if (tid == 0) TexA = 1.0f;
        float TA = __shfl(p, 63, 64);
        float wA = alpha0 * TexA;

        float mB = (tid < 32) ? (1.0f - alpha1 + EPSA) : 1.0f;
        float pb = mB;
#pragma unroll
        for (int off = 1; off < 32; off <<= 1) {
            float v = __shfl_up(pb, off, 64);
            if (tid >= off) pb *= v;
        }
        float TexB = __shfl_up(pb, 1, 64);
        if (tid == 0) TexB = 1.0f;
        float wB = (tid < 32) ? alpha1 * TexB * TA : 0.0f;

        float s0 = wA*r0c + wB*r1c;
        float s1 = wA*g0c + wB*g1c;
        float s2v = wA*b0c + wB*b1c;
#pragma unroll
        for (int off = 32; off; off >>= 1) {
            s0  += __shfl_xor(s0,  off, 64);
            s1  += __shfl_xor(s1,  off, 64);
            s2v += __shfl_xor(s2v, off, 64);
        }
        if (tid == 0) {
            out[3*r + 0] = s0;
            out[3*r + 1] = s1;
            out[3*r + 2] = s2v;
        }
    }
}

} // namespace

extern "C" void kernel_launch(void* const* d_in, const int* in_sizes, int n_in,
                              void* d_out, int out_size, void* d_ws, size_t ws_size,
                              hipStream_t stream) {
    const float* pixels = (const float*)d_in[0];
    const float* Cm  = (const float*)d_in[1];
    const float* Wm  = (const float*)d_in[2];
    const float* Sm  = (const float*)d_in[3];
    const float* W1  = (const float*)d_in[4];
    const float* b1  = (const float*)d_in[5];
    const float* W2  = (const float*)d_in[6];
    const float* b2  = (const float*)d_in[7];
    const float* Wc1 = (const float*)d_in[8];
    const float* bc1 = (const float*)d_in[9];
    const float* Wc2 = (const float*)d_in[10];
    const float* bc2 = (const float*)d_in[11];
    float* out = (float*)d_out;

    const int N = in_sizes[0] / 2;   // pixels is (B=1, N, 2)
    const size_t need = (size_t)N * 256 * sizeof(float4);   // 4 KB per ray
    if (ws_size >= need) {
        hipLaunchKernelGGL((render_k<true>), dim3(N), dim3(64), 0, stream,
                           pixels, Cm, Wm, Sm, W1, b1, W2, b2, Wc1, bc1, Wc2, bc2,
                           (float4*)d_ws, out, N);
    } else {
        hipLaunchKernelGGL((render_k<false>), dim3(N), dim3(64), 0, stream,
                           pixels, Cm, Wm, Sm, W1, b1, W2, b2, Wc1, bc1, Wc2, bc2,
                           nullptr, out, N);
    }
}

// Round 9
// 114.068 us; speedup vs baseline: 1.2409x; 1.2409x over previous
//
#include <hip/hip_runtime.h>
#include <math.h>

// Renderer: occupancy-field ray marching + secant + shading.
// R9: 4 rays per 64-lane wave (16 lanes/ray, 1024 blocks). Per-ray reparam
//     tables (R6 content) built cooperatively in LDS; each broadcast
//     ds_read_b128 now feeds 4 rays' worth of math: weight-load instrs drop
//     512/ray -> 96/ray (the R6 LDS-pipe ceiling, 45us of 47.9, was exactly
//     these loads). Phase2/secant/compositing use width-16 shuffle groups.
//     dfar==0 rays handled by the normal path (no crossing -> obj=false).

namespace {

constexpr int H_    = 128;
constexpr int RS    = 128;   // RAY_STEPS
constexpr int NSEC  = 8;
constexpr int SOUT_ = 32;    // STEPS_OUT
constexpr int SIN_  = 64;    // STEPS_IN
constexpr int FULL_ = 96;
constexpr int RPB   = 4;     // rays per block (one wave)
constexpr float EPSA   = 1e-6f;
constexpr float DELTA_ = 0.44626032029685964f; // max(2*exp(-1.5), 0.1)
constexpr float L2E    = 1.4426950408889634f;  // log2(e)
constexpr float LN2    = 0.6931471805599453f;

typedef __attribute__((ext_vector_type(2))) float f2;

__device__ __forceinline__ f2 s2(float v) { return f2{v, v}; }

// deg-6 poly for log2(1+e), e in [0,1], via t = 2e-1; max err ~1e-4.
constexpr float PC0 =  0.5849625007211562f;
constexpr float PC1 =  0.4808983469629878f;
constexpr float PC2 = -0.0801497244938313f;
constexpr float PC3 =  0.0178110498875181f;
constexpr float PC4 = -0.0044527624718795f;
constexpr float PC5 =  0.0011873633258345f;
constexpr float PC6 = -0.0003298231460651f;

// packed log2-domain softplus: sp2(u) = max(u,0) + log2(1 + 2^-|u|)
__device__ __forceinline__ f2 sp2p(f2 u) {
    f2 e;
    e.x = __builtin_amdgcn_exp2f(-fabsf(u.x));
    e.y = __builtin_amdgcn_exp2f(-fabsf(u.y));
    f2 t = e + e - 1.0f;
    f2 p = s2(PC6);
    p = __builtin_elementwise_fma(p, t, s2(PC5));
    p = __builtin_elementwise_fma(p, t, s2(PC4));
    p = __builtin_elementwise_fma(p, t, s2(PC3));
    p = __builtin_elementwise_fma(p, t, s2(PC2));
    p = __builtin_elementwise_fma(p, t, s2(PC1));
    p = __builtin_elementwise_fma(p, t, s2(PC0));
    return __builtin_elementwise_max(u, s2(0.0f)) + p;
}

__device__ __forceinline__ float sigmoid_fast(float x) {
    return __builtin_amdgcn_rcpf(1.0f + __expf(-x));
}
__device__ __forceinline__ float sgnf(float p) {
    return (p > 0.0f) ? 1.0f : ((p < 0.0f) ? -1.0f : 0.0f);
}
__device__ __forceinline__ float secant_step(float f_l, float f_h, float d_l, float d_h) {
    float den = f_h - f_l;
    if (fabsf(den) > 1e-12f) return -f_l * (d_h - d_l) / den + d_l;
    return 0.5f * (d_l + d_h);
}

__device__ void inv4(const float* m, float* o) {
    float inv[16];
    inv[0]  =  m[5]*m[10]*m[15] - m[5]*m[11]*m[14] - m[9]*m[6]*m[15] + m[9]*m[7]*m[14] + m[13]*m[6]*m[11] - m[13]*m[7]*m[10];
    inv[4]  = -m[4]*m[10]*m[15] + m[4]*m[11]*m[14] + m[8]*m[6]*m[15] - m[8]*m[7]*m[14] - m[12]*m[6]*m[11] + m[12]*m[7]*m[10];
    inv[8]  =  m[4]*m[9]*m[15]  - m[4]*m[11]*m[13] - m[8]*m[5]*m[15] + m[8]*m[7]*m[13] + m[12]*m[5]*m[11] - m[12]*m[7]*m[9];
    inv[12] = -m[4]*m[9]*m[14]  + m[4]*m[10]*m[13] + m[8]*m[5]*m[14] - m[8]*m[6]*m[13] - m[12]*m[5]*m[10] + m[12]*m[6]*m[9];
    inv[1]  = -m[1]*m[10]*m[15] + m[1]*m[11]*m[14] + m[9]*m[2]*m[15] - m[9]*m[3]*m[14] - m[13]*m[2]*m[11] + m[13]*m[3]*m[10];
    inv[5]  =  m[0]*m[10]*m[15] - m[0]*m[11]*m[14] - m[8]*m[2]*m[15] + m[8]*m[3]*m[14] + m[12]*m[2]*m[11] - m[12]*m[3]*m[10];
    inv[9]  = -m[0]*m[9]*m[15]  + m[0]*m[11]*m[13] + m[8]*m[1]*m[15] - m[8]*m[3]*m[13] - m[12]*m[1]*m[11] + m[12]*m[3]*m[9];
    inv[13] =  m[0]*m[9]*m[14]  - m[0]*m[10]*m[13] - m[8]*m[1]*m[14] + m[8]*m[2]*m[13] + m[12]*m[1]*m[10] - m[12]*m[2]*m[9];
    inv[2]  =  m[1]*m[6]*m[15]  - m[1]*m[7]*m[14]  - m[5]*m[2]*m[15] + m[5]*m[3]*m[14] + m[13]*m[2]*m[7]  - m[13]*m[3]*m[6];
    inv[6]  = -m[0]*m[6]*m[15]  + m[0]*m[7]*m[14]  + m[4]*m[2]*m[15] - m[4]*m[3]*m[14] - m[12]*m[2]*m[7]  + m[12]*m[3]*m[6];
    inv[10] =  m[0]*m[5]*m[15]  - m[0]*m[7]*m[13]  - m[4]*m[1]*m[15] + m[4]*m[3]*m[13] + m[12]*m[1]*m[7]  - m[12]*m[3]*m[5];
    inv[14] = -m[0]*m[5]*m[14]  + m[0]*m[6]*m[13]  + m[4]*m[1]*m[14] - m[4]*m[2]*m[13] - m[12]*m[1]*m[6]  + m[12]*m[2]*m[5];
    inv[3]  = -m[1]*m[6]*m[11]  + m[1]*m[7]*m[10]  + m[5]*m[2]*m[11] - m[5]*m[3]*m[10] - m[9]*m[2]*m[7]   + m[9]*m[3]*m[6];
    inv[7]  =  m[0]*m[6]*m[11]  - m[0]*m[7]*m[10]  - m[4]*m[2]*m[11] + m[4]*m[3]*m[10] + m[8]*m[2]*m[7]   - m[8]*m[3]*m[6];
    inv[11] = -m[0]*m[5]*m[11]  + m[0]*m[7]*m[9]   + m[4]*m[1]*m[11] - m[4]*m[3]*m[9]  - m[8]*m[1]*m[7]   + m[8]*m[3]*m[5];
    inv[15] =  m[0]*m[5]*m[10]  - m[0]*m[6]*m[9]   - m[4]*m[1]*m[10] + m[4]*m[2]*m[9]  + m[8]*m[1]*m[6]   - m[8]*m[2]*m[5];
    float det = m[0]*inv[0] + m[1]*inv[4] + m[2]*inv[8] + m[3]*inv[12];
    float idet = 1.0f / det;
    for (int i = 0; i < 16; i++) o[i] = inv[i] * idet;
}

__global__ __launch_bounds__(64) void render_k(
    const float* __restrict__ pixels,
    const float* __restrict__ Cm, const float* __restrict__ Wm, const float* __restrict__ Sm,
    const float* __restrict__ W1, const float* __restrict__ b1,
    const float* __restrict__ W2, const float* __restrict__ b2,
    const float* __restrict__ Wc1, const float* __restrict__ bc1,
    const float* __restrict__ Wc2, const float* __restrict__ bc2,
    float* __restrict__ out, int N)
{
    const int tid = threadIdx.x;      // 0..63
    const int g   = tid >> 4;         // ray group 0..3
    const int ll  = tid & 15;         // lane within group
    const int r0  = blockIdx.x * RPB;

    // per-ray reparam tables (slot = g*64 + j2, pair-major over hidden units)
    __shared__ float4 sA[RPB*64];     // {a, a', c, c'}       (occ, log2 domain)
    __shared__ float4 sB[RPB*64];     // {w, w', aC, aC'}     (w = w2*ln2)
    __shared__ float4 sC[RPB*64];     // {cC, cC', w0, w0'}
    __shared__ float4 sD[RPB*64];     // {w1c, w1c', w2c, w2c'}
    __shared__ __align__(16) float sval[RPB][RS];   // phase-1 logits
    __shared__ float4 sGeo[RPB][2];   // {rx,ry,rz,dfar}, {mint,-,-,-}
    __shared__ float  sInv[3][16];    // iC, iW, iS
    __shared__ float  sT[16], sM[16];

    // ---- matrices: one inv4 per matrix on lanes 0..2 (control-uniform) ----
    {
        const float* mm = (tid == 0) ? Cm : ((tid == 1) ? Wm : Sm);
        float o[16];
        inv4(mm, o);
        if (tid < 3)
            for (int k = 0; k < 16; k++) sInv[tid][k] = o[k];
    }
    __syncthreads();
    if (tid < 16) {                   // T = iW @ iC
        int row = tid >> 2, col = tid & 3;
        float s = 0.0f;
        for (int k = 0; k < 4; k++) s += sInv[1][row*4 + k] * sInv[0][k*4 + col];
        sT[tid] = s;
    }
    __syncthreads();
    if (tid < 16) {                   // M = iS @ T
        int row = tid >> 2, col = tid & 3;
        float s = 0.0f;
        for (int k = 0; k < 4; k++) s += sInv[2][row*4 + k] * sT[k*4 + col];
        sM[tid] = s;
    }
    __syncthreads();

    const float cx = sM[3], cy = sM[7], cz = sM[11];   // camera (uniform)

    // ---- ray setup: lanes 0..3, one ray each ----
    if (tid < RPB) {
        const int rr = min(r0 + tid, N - 1);
        const float px_ = pixels[2*rr], py_ = pixels[2*rr + 1];
        float dir[3];
        for (int i = 0; i < 3; i++) {
            float pw = sM[4*i + 0]*px_ + sM[4*i + 1]*py_ + sM[4*i + 2] + sM[4*i + 3];
            dir[i] = pw - sM[4*i + 3];
        }
        float nrm = sqrtf(dir[0]*dir[0] + dir[1]*dir[1] + dir[2]*dir[2]);
        float Rx = dir[0]/nrm, Ry = dir[1]/nrm, Rz = dir[2]/nrm;
        float rcd = Rx*cx + Ry*cy + Rz*cz;
        float cc  = cx*cx + cy*cy + cz*cz;
        float under = rcd*rcd - (cc - 1.0f);      // RADIUS = 1
        int mint = under > 0.0f;
        float s = sqrtf(mint ? under : 1.0f);
        float dfar = mint ? fmaxf(s - rcd, 0.0f) : 0.0f;
        sGeo[tid][0] = make_float4(Rx, Ry, Rz, dfar);
        sGeo[tid][1] = make_float4((float)mint, 0.0f, 0.0f, 0.0f);
    }
    __syncthreads();

    // ---- build per-ray reparam tables (R6 staging formulas, per ray) ----
    {
        const int u0_ = 2*tid, u1_ = 2*tid + 1;
        float w1x0=W1[u0_], w1y0=W1[H_+u0_], w1z0=W1[2*H_+u0_], b10=b1[u0_], w20=W2[u0_];
        float w1x1=W1[u1_], w1y1=W1[H_+u1_], w1z1=W1[2*H_+u1_], b11=b1[u1_], w21=W2[u1_];
        float q00=Wc1[u0_], q10=Wc1[H_+u0_], q20=Wc1[2*H_+u0_];
        float q30=Wc1[3*H_+u0_], q40=Wc1[4*H_+u0_], q50=Wc1[5*H_+u0_], bcA=bc1[u0_];
        float q01=Wc1[u1_], q11=Wc1[H_+u1_], q21=Wc1[2*H_+u1_];
        float q31=Wc1[3*H_+u1_], q41=Wc1[4*H_+u1_], q51=Wc1[5*H_+u1_], bcB=bc1[u1_];
        float wa0=Wc2[3*u0_+0], wb0=Wc2[3*u0_+1], wc0=Wc2[3*u0_+2];
        float wa1=Wc2[3*u1_+0], wb1=Wc2[3*u1_+1], wc1=Wc2[3*u1_+2];
        // ray-independent parts
        float cL0 = (w1x0*cx + w1y0*cy + w1z0*cz + b10) * L2E;
        float cL1 = (w1x1*cx + w1y1*cy + w1z1*cz + b11) * L2E;
        float wl0 = w20 * LN2, wl1 = w21 * LN2;
        float camC0 = q00*cx + q10*cy + q20*cz + bcA;
        float camC1 = q01*cx + q11*cy + q21*cz + bcB;
#pragma unroll
        for (int it = 0; it < RPB; it++) {
            float4 ge = sGeo[it][0];
            float Rx = ge.x, Ry = ge.y, Rz = ge.z;
            float a0 = (w1x0*Rx + w1y0*Ry + w1z0*Rz) * L2E;
            float a1 = (w1x1*Rx + w1y1*Ry + w1z1*Rz) * L2E;
            float aC0 = q00*Rx + q10*Ry + q20*Rz;
            float aC1 = q01*Rx + q11*Ry + q21*Rz;
            float cC0 = camC0 - (q30*Rx + q40*Ry + q50*Rz);
            float cC1 = camC1 - (q31*Rx + q41*Ry + q51*Rz);
            const int idx = it*64 + tid;
            sA[idx] = make_float4(a0, a1, cL0, cL1);
            sB[idx] = make_float4(wl0, wl1, aC0, aC1);
            sC[idx] = make_float4(cC0, cC1, wa0, wa1);
            sD[idx] = make_float4(wb0, wb1, wc0, wc1);
        }
    }
    const float b2v  = b2[0];
    const float bc20 = bc2[0], bc21 = bc2[1], bc22 = bc2[2];
    __syncthreads();

    // per-lane ray geometry
    const float4 ge = sGeo[g][0];
    const float rx = ge.x, ry = ge.y, rz = ge.z, dfar = ge.w;
    const int   mint = sGeo[g][1].x != 0.0f;
    const int   base = g*64;
    const float inv127 = 1.0f / (RS - 1);

    // ---- phase 1: steps 8ll..8ll+7, packed in 4 step-pairs ----
    float lg[8];
    {
        f2 dd[4], acc[4];
#pragma unroll
        for (int k = 0; k < 4; k++) {
            dd[k] = f2{ dfar * ((float)(8*ll + 2*k)     * inv127),
                        dfar * ((float)(8*ll + 2*k + 1) * inv127) };
            acc[k] = s2(0.0f);
        }
#pragma unroll 4
        for (int j2 = 0; j2 < 64; j2++) {
            float4 qa = sA[base + j2];
            float4 qb = sB[base + j2];
#pragma unroll
            for (int k = 0; k < 4; k++) {
                f2 uA = __builtin_elementwise_fma(s2(qa.x), dd[k], s2(qa.z));
                f2 uB = __builtin_elementwise_fma(s2(qa.y), dd[k], s2(qa.w));
                acc[k] = __builtin_elementwise_fma(sp2p(uA), s2(qb.x), acc[k]);
                acc[k] = __builtin_elementwise_fma(sp2p(uB), s2(qb.y), acc[k]);
            }
        }
#pragma unroll
        for (int k = 0; k < 4; k++) {
            lg[2*k]   = acc[k].x + b2v;
            lg[2*k+1] = acc[k].y + b2v;
        }
        float4* pv = (float4*)&sval[g][8*ll];
        pv[0] = make_float4(lg[0], lg[1], lg[2], lg[3]);
        pv[1] = make_float4(lg[4], lg[5], lg[6], lg[7]);
    }
    __syncthreads();

    // ---- phase 2: crossing detection + secant (width-16 groups) ----
    float dnp, dfp;
    int obj;
    {
        float v[8];
#pragma unroll
        for (int k = 0; k < 8; k++) v[k] = sigmoid_fast(lg[k]) - 0.5f;
        float vnext = __shfl_down(v[0], 1, 16);   // val[8ll+8]
        float cmin = 1e30f; int ind = 0;
#pragma unroll
        for (int k = 0; k < 8; k++) {
            int i = 8*ll + k;
            float c;
            if (i < RS - 1) {
                float nxt = (k < 7) ? v[k+1] : vnext;
                c = sgnf(v[k] * nxt) * (float)(RS - i);
            } else {
                c = 1.0f;
            }
            if (c < cmin) { cmin = c; ind = i; }
        }
#pragma unroll
        for (int off = 8; off; off >>= 1) {
            float c2 = __shfl_xor(cmin, off, 16);
            int   i2 = __shfl_xor(ind,  off, 16);
            if (c2 < cmin || (c2 == cmin && i2 < ind)) { cmin = c2; ind = i2; }
        }
        const int mask_0_free = (sigmoid_fast(sval[g][0]) - 0.5f) < 0.0f;
        const int mask_sc = cmin < 0.0f;
        const int ind_hi = min(ind + 1, RS - 1);
        const float f_low  = sigmoid_fast(sval[g][ind])    - 0.5f;
        const float f_high = sigmoid_fast(sval[g][ind_hi]) - 0.5f;
        const float d_low  = dfar * ((float)ind    * inv127);
        const float d_high = dfar * ((float)ind_hi * inv127);
        const int msk = mask_sc && (f_low < 0.0f) && mint && mask_0_free;

        float d_p = secant_step(f_low, f_high, d_low, d_high);
        if (msk) {   // group-uniform; whole 16-lane groups active together
            f2 aS[4], cS[4], wS[4];   // units 8ll..8ll+7 (pair-slots 4ll..4ll+3)
#pragma unroll
            for (int i = 0; i < 4; i++) {
                float4 qa = sA[base + 4*ll + i];
                float4 qb = sB[base + 4*ll + i];
                aS[i] = f2{qa.x, qa.y};
                cS[i] = f2{qa.z, qa.w};
                wS[i] = f2{qb.x, qb.y};
            }
            float d_l = d_low, f_l = f_low, d_h = d_high, f_h = f_high;
            for (int it = 0; it < NSEC; it++) {
                float part = 0.0f;
#pragma unroll
                for (int i = 0; i < 4; i++) {
                    f2 u = __builtin_elementwise_fma(aS[i], s2(d_p), cS[i]);
                    f2 sp = sp2p(u);
                    part += sp.x*wS[i].x + sp.y*wS[i].y;
                }
#pragma unroll
                for (int off = 8; off; off >>= 1) part += __shfl_xor(part, off, 16);
                float fm = sigmoid_fast(part + b2v) - 0.5f;
                bool low = fm < 0.0f;
                d_l = low ? d_p : d_l;  f_l = low ? fm : f_l;
                d_h = low ? d_h : d_p;  f_h = low ? f_h : fm;
                d_p = secant_step(f_l, f_h, d_l, d_h);
            }
        }
        float d_i;
        if (!mask_0_free)      d_i = 0.0f;
        else if (msk)          d_i = d_p;
        else                   d_i = INFINITY;
        int mask_zero = (d_i == 0.0f);
        int mask_pred = isfinite(d_i);
        float dists = mask_pred ? d_i : 1.0f;
        if (mask_zero) dists = 0.0f;
        obj = mask_pred && !mask_zero;
        dnp = fmaxf(dists - DELTA_, 0.0f);
        dfp = fminf(dists + DELTA_, dfar);
    }

    auto sample_d = [&](int s) -> float {
        if (obj) {
            if (s < SOUT_) return dnp * ((float)s * (1.0f / (SOUT_ - 1)));
            float u = (float)(s - SOUT_) * (1.0f / (SIN_ - 1));
            return dnp * (1.0f - u) + dfp * u;
        }
        return dfar * ((float)s * (1.0f / (FULL_ - 1)));
    };

    // ---- phase 3: samples 6ll..6ll+5, packed in 3 sample-pairs ----
    f2 SO[3], A0[3], A1[3], A2[3], DD[3];
#pragma unroll
    for (int p = 0; p < 3; p++) {
        DD[p] = f2{ sample_d(6*ll + 2*p), sample_d(6*ll + 2*p + 1) };
        SO[p] = s2(0.0f); A0[p] = s2(0.0f); A1[p] = s2(0.0f); A2[p] = s2(0.0f);
    }
#pragma unroll 2
    for (int j2 = 0; j2 < 64; j2++) {
        float4 qa = sA[base + j2];
        float4 qb = sB[base + j2];
        float4 qc = sC[base + j2];
        float4 qd = sD[base + j2];
#pragma unroll
        for (int p = 0; p < 3; p++) {
            f2 u0v = __builtin_elementwise_fma(s2(qa.x), DD[p], s2(qa.z));
            f2 u1v = __builtin_elementwise_fma(s2(qa.y), DD[p], s2(qa.w));
            SO[p] = __builtin_elementwise_fma(sp2p(u0v), s2(qb.x), SO[p]);
            SO[p] = __builtin_elementwise_fma(sp2p(u1v), s2(qb.y), SO[p]);
            f2 f0 = __builtin_elementwise_max(
                        __builtin_elementwise_fma(s2(qb.z), DD[p], s2(qc.x)), s2(0.0f));
            f2 f1 = __builtin_elementwise_max(
                        __builtin_elementwise_fma(s2(qb.w), DD[p], s2(qc.y)), s2(0.0f));
            A0[p] = __builtin_elementwise_fma(f0, s2(qc.z), A0[p]);
            A0[p] = __builtin_elementwise_fma(f1, s2(qc.w), A0[p]);
            A1[p] = __builtin_elementwise_fma(f0, s2(qd.x), A1[p]);
            A1[p] = __builtin_elementwise_fma(f1, s2(qd.y), A1[p]);
            A2[p] = __builtin_elementwise_fma(f0, s2(qd.z), A2[p]);
            A2[p] = __builtin_elementwise_fma(f1, s2(qd.w), A2[p]);
        }
    }

    // ---- compositing: lane-local 6 samples, then width-16 scan/reduce ----
    {
        float Tloc = 1.0f, p0 = 0.0f, p1 = 0.0f, p2 = 0.0f;
#pragma unroll
        for (int p = 0; p < 3; p++) {
#pragma unroll
            for (int e = 0; e < 2; e++) {
                float so = e ? SO[p].y : SO[p].x;
                float a0 = e ? A0[p].y : A0[p].x;
                float a1 = e ? A1[p].y : A1[p].x;
                float a2 = e ? A2[p].y : A2[p].x;
                float al = sigmoid_fast(so + b2v);
                float w  = al * Tloc;
                p0 = fmaf(w, sigmoid_fast(a0 + bc20), p0);
                p1 = fmaf(w, sigmoid_fast(a1 + bc21), p1);
                p2 = fmaf(w, sigmoid_fast(a2 + bc22), p2);
                Tloc *= (1.0f - al + EPSA);
            }
        }
        // exclusive cumprod of Tloc across the 16-lane group
        float sc = Tloc;
#pragma unroll
        for (int off = 1; off < 16; off <<= 1) {
            float v = __shfl_up(sc, off, 16);
            if (ll >= off) sc *= v;
        }
        float Tex = __shfl_up(sc, 1, 16);
        if (ll == 0) Tex = 1.0f;
        float c0 = Tex * p0, c1 = Tex * p1, c2 = Tex * p2;
#pragma unroll
        for (int off = 8; off; off >>= 1) {
            c0 += __shfl_xor(c0, off, 16);
            c1 += __shfl_xor(c1, off, 16);
            c2 += __shfl_xor(c2, off, 16);
        }
        const int r = r0 + g;
        if (ll == 0 && r < N) {
            out[3*r + 0] = c0;
            out[3*r + 1] = c1;
            out[3*r + 2] = c2;
        }
    }
}

} // namespace

extern "C" void kernel_launch(void* const* d_in, const int* in_sizes, int n_in,
                              void* d_out, int out_size, void* d_ws, size_t ws_size,
                              hipStream_t stream) {
    const float* pixels = (const float*)d_in[0];
    const float* Cm  = (const float*)d_in[1];
    const float* Wm  = (const float*)d_in[2];
    const float* Sm  = (const float*)d_in[3];
    const float* W1  = (const float*)d_in[4];
    const float* b1  = (const float*)d_in[5];
    const float* W2  = (const float*)d_in[6];
    const float* b2  = (const float*)d_in[7];
    const float* Wc1 = (const float*)d_in[8];
    const float* bc1 = (const float*)d_in[9];
    const float* Wc2 = (const float*)d_in[10];
    const float* bc2 = (const float*)d_in[11];
    float* out = (float*)d_out;

    const int N = in_sizes[0] / 2;   // pixels is (B=1, N, 2)
    const int blocks = (N + RPB - 1) / RPB;
    hipLaunchKernelGGL(render_k, dim3(blocks), dim3(64), 0, stream,
                       pixels, Cm, Wm, Sm, W1, b1, W2, b2, Wc1, bc1, Wc2, bc2, out, N);
}